// Round 2
// baseline (2082.194 us; speedup 1.0000x reference)
//
#include <hip/hip_runtime.h>
#include <hip/hip_bf16.h>

// Problem constants (fixed by the reference)
#define NN 8192
#define EE 131072
#define MUL 128
#define AA 10
#define RB 8
#define DEF 264          // RB + 2*MUL
#define INV_SQRT3 0.5773502691896258f
#define INV_SQRT128 0.08838834764831845f
#define INV_SQRT10 0.31622776601683794f
#define INV_SQRT264 0.06154574548966636f

// ---------------------------------------------------------------------------
// Workspace layout (float offsets). Total ~198 MB.
// ---------------------------------------------------------------------------
#define WS_US     ((size_t)0)                      // N*128
#define WS_UV     (WS_US   + (size_t)NN*128)       // N*384
#define WS_SRC    (WS_UV   + (size_t)NN*384)       // N*128
#define WS_TGT    (WS_SRC  + (size_t)NN*128)       // N*128
#define WS_MSGS   (WS_TGT  + (size_t)NN*128)       // N*256
#define WS_MSGV   (WS_MSGS + (size_t)NN*256)       // N*768
#define WS_DENS   (WS_MSGV + (size_t)NN*768)       // N
#define WS_COUNTS (WS_DENS + (size_t)NN)           // N ints
#define WS_OFFS   (WS_COUNTS + (size_t)NN)         // N+1 ints
#define WS_CURSOR (WS_OFFS + (size_t)(NN+4))       // N ints
#define WS_POS    (WS_CURSOR + (size_t)NN)         // E ints
#define WS_META   (WS_POS  + (size_t)EE)           // E*8 floats
#define WS_TPW    (WS_META + (size_t)EE*8)         // E*512 bf16 = E*256 float-slots

__device__ __forceinline__ float silu_f(float x) { return x / (1.f + __expf(-x)); }
__device__ __forceinline__ float sigm_f(float x) { return 1.f / (1.f + __expf(-x)); }

// ---------------------------------------------------------------------------
// CSR build: count -> scan -> scatter   (receiver-sorted edge slots)
// ---------------------------------------------------------------------------
__global__ __launch_bounds__(256) void csr_count(
    const int* __restrict__ edge_index, int* __restrict__ counts)
{
    int e = blockIdx.x * 256 + threadIdx.x;
    atomicAdd(&counts[edge_index[EE + e]], 1);
}

__global__ __launch_bounds__(1024) void csr_scan(
    const int* __restrict__ counts, int* __restrict__ offs, int* __restrict__ cursor)
{
    __shared__ int sums[1024];
    const int t = threadIdx.x;
    int local[8];
    int s = 0;
#pragma unroll
    for (int k = 0; k < 8; ++k) { local[k] = s; s += counts[t * 8 + k]; }
    sums[t] = s;
    __syncthreads();
    for (int d = 1; d < 1024; d <<= 1) {
        int v = (t >= d) ? sums[t - d] : 0;
        __syncthreads();
        sums[t] += v;
        __syncthreads();
    }
    int base = (t > 0) ? sums[t - 1] : 0;
#pragma unroll
    for (int k = 0; k < 8; ++k) {
        offs[t * 8 + k] = base + local[k];
        cursor[t * 8 + k] = base + local[k];
    }
    if (t == 1023) offs[8192] = sums[1023];
}

__global__ __launch_bounds__(256) void csr_scatter(
    const int* __restrict__ edge_index, int* __restrict__ cursor, int* __restrict__ pos)
{
    int e = blockIdx.x * 256 + threadIdx.x;
    pos[e] = atomicAdd(&cursor[edge_index[EE + e]], 1);
}

// ---------------------------------------------------------------------------
// Kernel A: per-node precompute.  sc (to d_out), us, uv, src_e, tgt_e (to ws)
// ---------------------------------------------------------------------------
#define NPB_A 8
__global__ __launch_bounds__(128) void node_pre(
    const float* __restrict__ node_attrs, const float* __restrict__ node_feats,
    const float* __restrict__ Wss, const float* __restrict__ Wsv,
    const float* __restrict__ Wus, const float* __restrict__ Wuv,
    const float* __restrict__ Wsrc, const float* __restrict__ Wtgt,
    float* __restrict__ sc_out, float* __restrict__ us, float* __restrict__ uv,
    float* __restrict__ srcE, float* __restrict__ tgtE)
{
    __shared__ float s_l[NPB_A][128];
    __shared__ float v_l[NPB_A][384];
    __shared__ float a_l[NPB_A][AA];
    const int j = threadIdx.x;
    const int n0 = blockIdx.x * NPB_A;

    for (int idx = j; idx < NPB_A * 512; idx += 128) {
        int e = idx >> 9, k = idx & 511;
        float val = node_feats[(size_t)(n0 + e) * 512 + k];
        if (k < 128) s_l[e][k] = val; else v_l[e][k - 128] = val;
    }
    for (int idx = j; idx < NPB_A * AA; idx += 128) {
        int e = idx / AA, k = idx - e * AA;
        a_l[e][k] = node_attrs[(size_t)(n0 + e) * AA + k];
    }
    __syncthreads();

    float accS[NPB_A] = {0}, accU[NPB_A] = {0};
    float accSV[NPB_A][3] = {{0}}, accUV[NPB_A][3] = {{0}};
    float accSrc[NPB_A] = {0}, accTgt[NPB_A] = {0};

#pragma unroll 4
    for (int i = 0; i < 128; ++i) {
        float ws = Wss[i * 128 + j], wu = Wus[i * 128 + j];
#pragma unroll
        for (int e = 0; e < NPB_A; ++e) {
            float sv = s_l[e][i];
            accS[e] += sv * ws; accU[e] += sv * wu;
        }
    }
#pragma unroll 2
    for (int i = 0; i < 128; ++i) {
        float wsv = Wsv[i * 128 + j], wuv = Wuv[i * 128 + j];
#pragma unroll
        for (int e = 0; e < NPB_A; ++e) {
#pragma unroll
            for (int c = 0; c < 3; ++c) {
                float vv = v_l[e][i * 3 + c];
                accSV[e][c] += vv * wsv; accUV[e][c] += vv * wuv;
            }
        }
    }
#pragma unroll
    for (int i = 0; i < AA; ++i) {
        float w1 = Wsrc[i * 128 + j], w2 = Wtgt[i * 128 + j];
#pragma unroll
        for (int e = 0; e < NPB_A; ++e) {
            float av = a_l[e][i];
            accSrc[e] += av * w1; accTgt[e] += av * w2;
        }
    }

#pragma unroll
    for (int e = 0; e < NPB_A; ++e) {
        size_t n = n0 + e;
        sc_out[n * 512 + j] = accS[e] * INV_SQRT128;
#pragma unroll
        for (int c = 0; c < 3; ++c)
            sc_out[n * 512 + 128 + j * 3 + c] = accSV[e][c] * INV_SQRT128;
        us[n * 128 + j] = accU[e] * INV_SQRT128;
#pragma unroll
        for (int c = 0; c < 3; ++c)
            uv[n * 384 + j * 3 + c] = accUV[e][c] * INV_SQRT128;
        srcE[n * 128 + j] = accSrc[e] * INV_SQRT10;
        tgtE[n * 128 + j] = accTgt[e] * INV_SQRT10;
    }
}

// ---------------------------------------------------------------------------
// Kernel B: per-edge MLPs -> tpw (bf16, permuted into CSR slot order) + meta.
// block = 256 threads (4 waves), 32 edges/block, 8 edges/wave. No atomics.
// tpw is pre-scaled: chunks q<2 get 0.125*y0; q2,3: 0.125/sqrt3;
//                    q4,5: 0.125*y0/sqrt3; q6,7: 0.125/sqrt3.
// meta[slot] = {snd_bits, y1x, y1y, y1z, edge_density, pad...}
// ---------------------------------------------------------------------------
#define EB2 32
__global__ __launch_bounds__(256) void edge_mlp(
    const float* __restrict__ edge_attrs, const float* __restrict__ edge_feats,
    const int* __restrict__ edge_index,
    const float* __restrict__ srcE, const float* __restrict__ tgtE,
    const float* __restrict__ Wr0, const float* __restrict__ Wr1,
    const float* __restrict__ Wr2, const float* __restrict__ Wr3,
    const float* __restrict__ Wd0, const float* __restrict__ Wd1,
    const int* __restrict__ pos,
    __hip_bfloat16* __restrict__ tpwP, float* __restrict__ metaP)
{
    __shared__ float ef[EB2][DEF];
    __shared__ float hA[EB2][64];
    __shared__ float hB[EB2][64];
    __shared__ int   snd_l[EB2], rcv_l[EB2], slot_l[EB2];
    __shared__ float y_l[EB2][4];

    const int t = threadIdx.x;
    const int j = t & 63;
    const int w = t >> 6;
    const int e0 = blockIdx.x * EB2;

    if (t < EB2) {
        snd_l[t]  = edge_index[e0 + t];
        rcv_l[t]  = edge_index[EE + e0 + t];
        slot_l[t] = pos[e0 + t];
    }
    if (t >= 64 && t < 64 + EB2 * 4) {
        int tt = t - 64, e = tt >> 2, k = tt & 3;
        y_l[e][k] = edge_attrs[(size_t)(e0 + e) * 4 + k];
    }
    __syncthreads();

    // meta (except density, written later)
    if (t < EB2) {
        size_t mo = (size_t)slot_l[t] * 8;
        metaP[mo + 0] = __int_as_float(snd_l[t]);
        metaP[mo + 1] = y_l[t][1];
        metaP[mo + 2] = y_l[t][2];
        metaP[mo + 3] = y_l[t][3];
    }

    // stage ef = [edge_feats | srcE[snd] | tgtE[rcv]]
    for (int idx = t; idx < EB2 * DEF; idx += 256) {
        int e = idx / DEF, k = idx - e * DEF;
        float v;
        if (k < RB)            v = edge_feats[(size_t)(e0 + e) * RB + k];
        else if (k < RB + 128) v = srcE[(size_t)snd_l[e] * 128 + (k - RB)];
        else                   v = tgtE[(size_t)rcv_l[e] * 128 + (k - RB - 128)];
        ef[e][k] = v;
    }
    __syncthreads();

    const int eb = w * 8;

    // ---- h0 = silu(ef@Wr0 /sqrt264), d = silu(ef@Wd0 /sqrt264)
    float acc[8], dac[8];
#pragma unroll
    for (int k2 = 0; k2 < 8; ++k2) { acc[k2] = 0.f; dac[k2] = 0.f; }
    for (int i = 0; i < DEF; i += 4) {
        float4 efv[8];
#pragma unroll
        for (int k2 = 0; k2 < 8; ++k2)
            efv[k2] = *reinterpret_cast<const float4*>(&ef[eb + k2][i]);
#pragma unroll
        for (int ii = 0; ii < 4; ++ii) {
            float wr = Wr0[(i + ii) * 64 + j], wd = Wd0[(i + ii) * 64 + j];
#pragma unroll
            for (int k2 = 0; k2 < 8; ++k2) {
                float v = (&efv[k2].x)[ii];
                acc[k2] += v * wr; dac[k2] += v * wd;
            }
        }
    }
    float dreg[8];
#pragma unroll
    for (int k2 = 0; k2 < 8; ++k2) {
        hA[eb + k2][j] = silu_f(acc[k2] * INV_SQRT264);
        dreg[k2] = silu_f(dac[k2] * INV_SQRT264);
    }
    // density scalar per edge: tanh((d.Wd1/8)^2)
    {
        float wd1 = Wd1[j];
        float p[8];
#pragma unroll
        for (int k2 = 0; k2 < 8; ++k2) p[k2] = dreg[k2] * wd1;
#pragma unroll
        for (int m = 1; m < 64; m <<= 1) {
#pragma unroll
            for (int k2 = 0; k2 < 8; ++k2) p[k2] += __shfl_xor(p[k2], m);
        }
        if (j == 0) {
#pragma unroll
            for (int k2 = 0; k2 < 8; ++k2) {
                float tq = p[k2] * 0.125f;
                metaP[(size_t)slot_l[eb + k2] * 8 + 4] = tanhf(tq * tq);
            }
        }
    }
    __syncthreads();

    // ---- h1 = silu(h0@Wr1 /8)
#pragma unroll
    for (int k2 = 0; k2 < 8; ++k2) acc[k2] = 0.f;
    for (int i = 0; i < 64; i += 4) {
        float4 hv[8];
#pragma unroll
        for (int k2 = 0; k2 < 8; ++k2)
            hv[k2] = *reinterpret_cast<const float4*>(&hA[eb + k2][i]);
#pragma unroll
        for (int ii = 0; ii < 4; ++ii) {
            float wr = Wr1[(i + ii) * 64 + j];
#pragma unroll
            for (int k2 = 0; k2 < 8; ++k2) acc[k2] += (&hv[k2].x)[ii] * wr;
        }
    }
    __syncthreads();
#pragma unroll
    for (int k2 = 0; k2 < 8; ++k2) hB[eb + k2][j] = silu_f(acc[k2] * 0.125f);
    __syncthreads();

    // ---- h2 = silu(h1@Wr2 /8)
#pragma unroll
    for (int k2 = 0; k2 < 8; ++k2) acc[k2] = 0.f;
    for (int i = 0; i < 64; i += 4) {
        float4 hv[8];
#pragma unroll
        for (int k2 = 0; k2 < 8; ++k2)
            hv[k2] = *reinterpret_cast<const float4*>(&hB[eb + k2][i]);
#pragma unroll
        for (int ii = 0; ii < 4; ++ii) {
            float wr = Wr2[(i + ii) * 64 + j];
#pragma unroll
            for (int k2 = 0; k2 < 8; ++k2) acc[k2] += (&hv[k2].x)[ii] * wr;
        }
    }
    __syncthreads();
#pragma unroll
    for (int k2 = 0; k2 < 8; ++k2) hA[eb + k2][j] = silu_f(acc[k2] * 0.125f);
    __syncthreads();

    // ---- tpw = h2@Wr3 /8 (8 chunks of 64), scaled, stored bf16 at slot
    for (int q = 0; q < 8; ++q) {
        float a2[8];
#pragma unroll
        for (int k2 = 0; k2 < 8; ++k2) a2[k2] = 0.f;
        for (int i = 0; i < 64; i += 4) {
            float4 hv[8];
#pragma unroll
            for (int k2 = 0; k2 < 8; ++k2)
                hv[k2] = *reinterpret_cast<const float4*>(&hA[eb + k2][i]);
#pragma unroll
            for (int ii = 0; ii < 4; ++ii) {
                float wr = Wr3[(i + ii) * 512 + q * 64 + j];
#pragma unroll
                for (int k2 = 0; k2 < 8; ++k2) a2[k2] += (&hv[k2].x)[ii] * wr;
            }
        }
#pragma unroll
        for (int k2 = 0; k2 < 8; ++k2) {
            float y0 = y_l[eb + k2][0];
            float scale = (q < 2) ? 0.125f * y0
                        : (q < 4) ? 0.125f * INV_SQRT3
                        : (q < 6) ? 0.125f * y0 * INV_SQRT3
                                  : 0.125f * INV_SQRT3;
            tpwP[(size_t)slot_l[eb + k2] * 512 + q * 64 + j] =
                __float2bfloat16(a2[k2] * scale);
        }
    }
}

// ---------------------------------------------------------------------------
// Kernel C: per-node gather (no atomics). block = 128 threads, 1 node.
// msg_s[u]     = sum_e w1*xs          (y0, 0.125 folded into w1)
// msg_s[128+u] = sum_e w4*(xv.y1)     (invsqrt3, 0.125 folded)
// msg_v[u,c]   = sum_e w2*xs*y1[c]    (invsqrt3, 0.125 folded)
// msg_v[128+u,c]= sum_e w3*xv[c]      (y0, invsqrt3, 0.125 folded)
// ---------------------------------------------------------------------------
__global__ __launch_bounds__(128) void node_gather(
    const __hip_bfloat16* __restrict__ tpwP, const float* __restrict__ metaP,
    const int* __restrict__ offs,
    const float* __restrict__ us, const float* __restrict__ uv,
    float* __restrict__ msg_s, float* __restrict__ msg_v,
    float* __restrict__ density)
{
    const int n = blockIdx.x;
    const int j = threadIdx.x;
    const int s0 = offs[n], s1 = offs[n + 1];

    float as0 = 0.f, as1 = 0.f;
    float av0x = 0.f, av0y = 0.f, av0z = 0.f;
    float av1x = 0.f, av1y = 0.f, av1z = 0.f;
    float dsum = 0.f;

    for (int s = s0; s < s1; ++s) {
        const float4 m0 = *reinterpret_cast<const float4*>(&metaP[(size_t)s * 8]);
        const float dns = metaP[(size_t)s * 8 + 4];
        const int snd = __float_as_int(m0.x);
        const float y1x = m0.y, y1y = m0.z, y1z = m0.w;
        dsum += dns;

        const float xs = us[(size_t)snd * 128 + j];
        const float* xvp = &uv[(size_t)snd * 384 + 3 * j];
        const float xvx = xvp[0], xvy = xvp[1], xvz = xvp[2];

        const __hip_bfloat16* tp = &tpwP[(size_t)s * 512];
        const float w1 = __bfloat162float(tp[j]);
        const float w2 = __bfloat162float(tp[128 + j]);
        const float w3 = __bfloat162float(tp[256 + j]);
        const float w4 = __bfloat162float(tp[384 + j]);

        as0 += w1 * xs;
        as1 += w4 * (xvx * y1x + xvy * y1y + xvz * y1z);
        const float b2 = w2 * xs;
        av0x += b2 * y1x; av0y += b2 * y1y; av0z += b2 * y1z;
        av1x += w3 * xvx; av1y += w3 * xvy; av1z += w3 * xvz;
    }

    msg_s[(size_t)n * 256 + j] = as0;
    msg_s[(size_t)n * 256 + 128 + j] = as1;
    float* mv = &msg_v[(size_t)n * 768];
    mv[3 * j + 0] = av0x; mv[3 * j + 1] = av0y; mv[3 * j + 2] = av0z;
    mv[384 + 3 * j + 0] = av1x; mv[384 + 3 * j + 1] = av1y; mv[384 + 3 * j + 2] = av1z;
    if (j == 0) density[n] = dsum;
}

// ---------------------------------------------------------------------------
// Kernel D: per-node epilogue (W1/Wres, gate, W2) -> out
// ---------------------------------------------------------------------------
#define NPB_C 8
__global__ __launch_bounds__(128) void node_post(
    const float* __restrict__ msg_s, const float* __restrict__ msg_v,
    const float* __restrict__ density,
    const float* __restrict__ us, const float* __restrict__ uv,
    const float* __restrict__ W1s, const float* __restrict__ W1v,
    const float* __restrict__ Wrs, const float* __restrict__ Wrv,
    const float* __restrict__ W2s, const float* __restrict__ W2v,
    const float* __restrict__ alpha_p, const float* __restrict__ beta_p,
    float* __restrict__ out)
{
    __shared__ float ms_l[NPB_C][256];
    __shared__ float mv_l[NPB_C][768];
    __shared__ float us_l[NPB_C][128];
    __shared__ float uv_l[NPB_C][384];
    __shared__ float den_l[NPB_C];
    const int j = threadIdx.x;
    const int n0 = blockIdx.x * NPB_C;
    const float alpha = *alpha_p, beta = *beta_p;

    for (int idx = j; idx < NPB_C * 256; idx += 128) {
        int e = idx >> 8, k = idx & 255;
        ms_l[e][k] = msg_s[(size_t)(n0 + e) * 256 + k];
    }
    for (int idx = j; idx < NPB_C * 768; idx += 128) {
        int e = idx / 768, k = idx - e * 768;
        mv_l[e][k] = msg_v[(size_t)(n0 + e) * 768 + k];
    }
    for (int idx = j; idx < NPB_C * 128; idx += 128) {
        int e = idx >> 7, k = idx & 127;
        us_l[e][k] = us[(size_t)(n0 + e) * 128 + k];
    }
    for (int idx = j; idx < NPB_C * 384; idx += 128) {
        int e = idx / 384, k = idx - e * 384;
        uv_l[e][k] = uv[(size_t)(n0 + e) * 384 + k];
    }
    if (j < NPB_C) den_l[j] = density[n0 + j];
    __syncthreads();

    float mA[NPB_C] = {0}, mB[NPB_C] = {0}, mV[NPB_C][3] = {{0}};
#pragma unroll 2
    for (int i = 0; i < 256; ++i) {
        float w1 = W1s[i * 256 + j], w2 = W1s[i * 256 + 128 + j], wv = W1v[i * 128 + j];
#pragma unroll
        for (int e = 0; e < NPB_C; ++e) {
            float msv = ms_l[e][i];
            mA[e] += msv * w1; mB[e] += msv * w2;
#pragma unroll
            for (int c = 0; c < 3; ++c) mV[e][c] += mv_l[e][i * 3 + c] * wv;
        }
    }
    float rA[NPB_C] = {0}, rB[NPB_C] = {0}, rV[NPB_C][3] = {{0}};
#pragma unroll 2
    for (int i = 0; i < 128; ++i) {
        float w1 = Wrs[i * 256 + j], w2 = Wrs[i * 256 + 128 + j], wv = Wrv[i * 128 + j];
#pragma unroll
        for (int e = 0; e < NPB_C; ++e) {
            float sv = us_l[e][i];
            rA[e] += sv * w1; rB[e] += sv * w2;
#pragma unroll
            for (int c = 0; c < 3; ++c) rV[e][c] += uv_l[e][i * 3 + c] * wv;
        }
    }
    __syncthreads();  // done reading us_l/uv_l; reuse as out_s/out_v

#pragma unroll
    for (int e = 0; e < NPB_C; ++e) {
        float invden = 1.f / (den_l[e] * beta + alpha);
        float m1 = mA[e] * 0.0625f * invden + rA[e] * INV_SQRT128;
        float m2 = mB[e] * 0.0625f * invden + rB[e] * INV_SQRT128;
        float gate = sigm_f(m2);
        us_l[e][j] = silu_f(m1);
#pragma unroll
        for (int c = 0; c < 3; ++c)
            uv_l[e][j * 3 + c] = (mV[e][c] * 0.0625f * invden + rV[e][c] * INV_SQRT128) * gate;
    }
    __syncthreads();

    float fS[NPB_C] = {0}, fV[NPB_C][3] = {{0}};
#pragma unroll 2
    for (int i = 0; i < 128; ++i) {
        float w1 = W2s[i * 128 + j], wv = W2v[i * 128 + j];
#pragma unroll
        for (int e = 0; e < NPB_C; ++e) {
            fS[e] += us_l[e][i] * w1;
#pragma unroll
            for (int c = 0; c < 3; ++c) fV[e][c] += uv_l[e][i * 3 + c] * wv;
        }
    }
#pragma unroll
    for (int e = 0; e < NPB_C; ++e) {
        size_t n = n0 + e;
        float4 o;
        o.x = fS[e] * INV_SQRT128;
        o.y = fV[e][0] * INV_SQRT128;
        o.z = fV[e][1] * INV_SQRT128;
        o.w = fV[e][2] * INV_SQRT128;
        reinterpret_cast<float4*>(out)[n * 128 + j] = o;
    }
}

// ---------------------------------------------------------------------------
extern "C" void kernel_launch(void* const* d_in, const int* in_sizes, int n_in,
                              void* d_out, int out_size, void* d_ws, size_t ws_size,
                              hipStream_t stream)
{
    const float* node_attrs = (const float*)d_in[0];
    const float* node_feats = (const float*)d_in[1];
    const float* edge_attrs = (const float*)d_in[2];
    const float* edge_feats = (const float*)d_in[3];
    const int*   edge_index = (const int*)d_in[4];
    const float* W_skip_s = (const float*)d_in[5];
    const float* W_skip_v = (const float*)d_in[6];
    const float* W_up_s   = (const float*)d_in[7];
    const float* W_up_v   = (const float*)d_in[8];
    const float* W_src    = (const float*)d_in[9];
    const float* W_tgt    = (const float*)d_in[10];
    const float* W_r0     = (const float*)d_in[11];
    const float* W_r1     = (const float*)d_in[12];
    const float* W_r2     = (const float*)d_in[13];
    const float* W_r3     = (const float*)d_in[14];
    const float* W_d0     = (const float*)d_in[15];
    const float* W_d1     = (const float*)d_in[16];
    const float* W1_s     = (const float*)d_in[17];
    const float* W1_v     = (const float*)d_in[18];
    const float* Wres_s   = (const float*)d_in[19];
    const float* Wres_v   = (const float*)d_in[20];
    const float* W2_s     = (const float*)d_in[21];
    const float* W2_v     = (const float*)d_in[22];
    const float* alpha_p  = (const float*)d_in[23];
    const float* beta_p   = (const float*)d_in[24];

    float* out = (float*)d_out;
    float* sc_out = out + (size_t)NN * 512;
    float* ws = (float*)d_ws;

    float* us    = ws + WS_US;
    float* uv    = ws + WS_UV;
    float* srcE  = ws + WS_SRC;
    float* tgtE  = ws + WS_TGT;
    float* msgS  = ws + WS_MSGS;
    float* msgV  = ws + WS_MSGV;
    float* dens  = ws + WS_DENS;
    int*   counts = (int*)(ws + WS_COUNTS);
    int*   offs   = (int*)(ws + WS_OFFS);
    int*   cursor = (int*)(ws + WS_CURSOR);
    int*   pos    = (int*)(ws + WS_POS);
    float* metaP  = ws + WS_META;
    __hip_bfloat16* tpwP = (__hip_bfloat16*)(ws + WS_TPW);

    hipMemsetAsync(counts, 0, (size_t)NN * sizeof(int), stream);

    csr_count<<<EE / 256, 256, 0, stream>>>(edge_index, counts);
    csr_scan<<<1, 1024, 0, stream>>>(counts, offs, cursor);
    csr_scatter<<<EE / 256, 256, 0, stream>>>(edge_index, cursor, pos);

    node_pre<<<NN / NPB_A, 128, 0, stream>>>(
        node_attrs, node_feats, W_skip_s, W_skip_v, W_up_s, W_up_v, W_src, W_tgt,
        sc_out, us, uv, srcE, tgtE);

    edge_mlp<<<EE / EB2, 256, 0, stream>>>(
        edge_attrs, edge_feats, edge_index, srcE, tgtE,
        W_r0, W_r1, W_r2, W_r3, W_d0, W_d1, pos, tpwP, metaP);

    node_gather<<<NN, 128, 0, stream>>>(
        tpwP, metaP, offs, us, uv, msgS, msgV, dens);

    node_post<<<NN / NPB_C, 128, 0, stream>>>(
        msgS, msgV, dens, us, uv, W1_s, W1_v, Wres_s, Wres_v, W2_s, W2_v,
        alpha_p, beta_p, out);
}

// Round 3
// 606.574 us; speedup vs baseline: 3.4327x; 3.4327x over previous
//
#include <hip/hip_runtime.h>

// Problem constants (fixed by the reference)
#define NN 8192
#define EE 131072
#define MUL 128
#define AA 10
#define RB 8
#define DEF 264          // RB + 2*MUL
#define INV_SQRT3 0.5773502691896258f
#define INV_SQRT128 0.08838834764831845f
#define INV_SQRT10 0.31622776601683794f
#define INV_SQRT264 0.06154574548966636f

typedef __attribute__((ext_vector_type(8))) short short8;
typedef __attribute__((ext_vector_type(4))) float floatx4;

// ---------------------------------------------------------------------------
// Workspace layout (float offsets).
// ---------------------------------------------------------------------------
#define WS_US     ((size_t)0)                      // N*128 f32
#define WS_UV     (WS_US   + (size_t)NN*128)       // N*384 f32
#define WS_SRC    (WS_UV   + (size_t)NN*384)       // N*128 (holds bf16, uses half)
#define WS_TGT    (WS_SRC  + (size_t)NN*128)       // N*128 (holds bf16)
#define WS_MSGS   (WS_TGT  + (size_t)NN*128)       // N*256 f32 (WB overlaid pre-gather)
#define WS_MSGV   (WS_MSGS + (size_t)NN*256)       // N*768 f32
#define WS_DENS   (WS_MSGV + (size_t)NN*768)       // N
#define WS_COUNTS (WS_DENS + (size_t)NN)           // N ints
#define WS_OFFS   (WS_COUNTS + (size_t)NN)         // N+1 ints
#define WS_CURSOR (WS_OFFS + (size_t)(NN+4))       // N ints
#define WS_POS    (WS_CURSOR + (size_t)NN)         // E ints
#define WS_META   (WS_POS  + (size_t)EE)           // E*8 floats
#define WS_TPW    (WS_META + (size_t)EE*8)         // E*512 bf16 = E*256 float-slots

__device__ __forceinline__ float silu_f(float x) { return x / (1.f + __expf(-x)); }
__device__ __forceinline__ float sigm_f(float x) { return 1.f / (1.f + __expf(-x)); }

__device__ __forceinline__ unsigned short f2bf(float x) {
    union { float f; unsigned u; } uf; uf.f = x;
    unsigned r = uf.u + 0x7FFFu + ((uf.u >> 16) & 1u);   // RNE
    return (unsigned short)(r >> 16);
}
__device__ __forceinline__ float bf2f(unsigned short b) {
    union { unsigned u; float f; } uf; uf.u = ((unsigned)b) << 16;
    return uf.f;
}

// ---------------------------------------------------------------------------
// CSR build: count -> scan -> scatter   (receiver-sorted edge slots)
// ---------------------------------------------------------------------------
__global__ __launch_bounds__(256) void csr_count(
    const int* __restrict__ edge_index, int* __restrict__ counts)
{
    int e = blockIdx.x * 256 + threadIdx.x;
    atomicAdd(&counts[edge_index[EE + e]], 1);
}

__global__ __launch_bounds__(1024) void csr_scan(
    const int* __restrict__ counts, int* __restrict__ offs, int* __restrict__ cursor)
{
    __shared__ int sums[1024];
    const int t = threadIdx.x;
    int local[8];
    int s = 0;
#pragma unroll
    for (int k = 0; k < 8; ++k) { local[k] = s; s += counts[t * 8 + k]; }
    sums[t] = s;
    __syncthreads();
    for (int d = 1; d < 1024; d <<= 1) {
        int v = (t >= d) ? sums[t - d] : 0;
        __syncthreads();
        sums[t] += v;
        __syncthreads();
    }
    int base = (t > 0) ? sums[t - 1] : 0;
#pragma unroll
    for (int k = 0; k < 8; ++k) {
        offs[t * 8 + k] = base + local[k];
        cursor[t * 8 + k] = base + local[k];
    }
    if (t == 1023) offs[8192] = sums[1023];
}

__global__ __launch_bounds__(256) void csr_scatter(
    const int* __restrict__ edge_index, int* __restrict__ cursor, int* __restrict__ pos)
{
    int e = blockIdx.x * 256 + threadIdx.x;
    pos[e] = atomicAdd(&cursor[edge_index[EE + e]], 1);
}

// ---------------------------------------------------------------------------
// Weight pre-swizzle into MFMA B-fragment order (bf16, scales folded).
// frag layout: [frag][lane][8] where lane gives k0=(lane>>4)*8, n=lane&15.
// L0: KT=9 NT=8 (W_r0|W_d0, K padded 264->288, x INV_SQRT264)     frag 0..71
// L1: KT=2 NT=4 (W_r1 x 0.125)                                    frag 72..79
// L2: KT=2 NT=4 (W_r2 x 0.125)                                    frag 80..87
// L3: KT=2 NT=32 (W_r3 x 0.125 or 0.125*INV_SQRT3 per chunk)      frag 88..151
// 152 frags * 64 lanes = 9728 threads = 38 blocks * 256
// ---------------------------------------------------------------------------
__global__ __launch_bounds__(256) void swizzle_weights(
    const float* __restrict__ Wr0, const float* __restrict__ Wd0,
    const float* __restrict__ Wr1, const float* __restrict__ Wr2,
    const float* __restrict__ Wr3,
    unsigned short* __restrict__ WB0, unsigned short* __restrict__ WB1,
    unsigned short* __restrict__ WB2, unsigned short* __restrict__ WB3)
{
    int fid = blockIdx.x * 256 + threadIdx.x;
    int lane = fid & 63;
    int frag = fid >> 6;
    int k0 = (lane >> 4) * 8;
    int n0 = lane & 15;
    unsigned short o[8];
    unsigned short* dst;

    if (frag < 72) {
        int kt = frag >> 3, nt = frag & 7;
        int n = nt * 16 + n0;
#pragma unroll
        for (int j = 0; j < 8; ++j) {
            int k = kt * 32 + k0 + j;
            float v = 0.f;
            if (k < 264) v = ((n < 64) ? Wr0[k * 64 + n] : Wd0[k * 64 + (n - 64)]) * INV_SQRT264;
            o[j] = f2bf(v);
        }
        dst = WB0 + (size_t)fid * 8;
    } else if (frag < 80) {
        int fl = frag - 72;
        int kt = fl >> 2, nt = fl & 3;
        int n = nt * 16 + n0;
#pragma unroll
        for (int j = 0; j < 8; ++j) {
            int k = kt * 32 + k0 + j;
            o[j] = f2bf(Wr1[k * 64 + n] * 0.125f);
        }
        dst = WB1 + (size_t)(fid - 72 * 64) * 8;
    } else if (frag < 88) {
        int fl = frag - 80;
        int kt = fl >> 2, nt = fl & 3;
        int n = nt * 16 + n0;
#pragma unroll
        for (int j = 0; j < 8; ++j) {
            int k = kt * 32 + k0 + j;
            o[j] = f2bf(Wr2[k * 64 + n] * 0.125f);
        }
        dst = WB2 + (size_t)(fid - 80 * 64) * 8;
    } else {
        int fl = frag - 88;
        int kt = fl >> 5, nt = fl & 31;
        int n = nt * 16 + n0;
        int q = n >> 6;
        float sc = (q < 2) ? 0.125f : 0.125f * INV_SQRT3;
#pragma unroll
        for (int j = 0; j < 8; ++j) {
            int k = kt * 32 + k0 + j;
            o[j] = f2bf(Wr3[k * 512 + n] * sc);
        }
        dst = WB3 + (size_t)(fid - 88 * 64) * 8;
    }
    uint4 pk;
    pk.x = (unsigned)o[0] | ((unsigned)o[1] << 16);
    pk.y = (unsigned)o[2] | ((unsigned)o[3] << 16);
    pk.z = (unsigned)o[4] | ((unsigned)o[5] << 16);
    pk.w = (unsigned)o[6] | ((unsigned)o[7] << 16);
    *(uint4*)dst = pk;
}

// ---------------------------------------------------------------------------
// Kernel A: per-node precompute.  sc (to d_out), us/uv (f32), srcE/tgtE (bf16)
// ---------------------------------------------------------------------------
#define NPB_A 8
__global__ __launch_bounds__(128) void node_pre(
    const float* __restrict__ node_attrs, const float* __restrict__ node_feats,
    const float* __restrict__ Wss, const float* __restrict__ Wsv,
    const float* __restrict__ Wus, const float* __restrict__ Wuv,
    const float* __restrict__ Wsrc, const float* __restrict__ Wtgt,
    float* __restrict__ sc_out, float* __restrict__ us, float* __restrict__ uv,
    unsigned short* __restrict__ srcEb, unsigned short* __restrict__ tgtEb)
{
    __shared__ float s_l[NPB_A][128];
    __shared__ float v_l[NPB_A][384];
    __shared__ float a_l[NPB_A][AA];
    const int j = threadIdx.x;
    const int n0 = blockIdx.x * NPB_A;

    for (int idx = j; idx < NPB_A * 512; idx += 128) {
        int e = idx >> 9, k = idx & 511;
        float val = node_feats[(size_t)(n0 + e) * 512 + k];
        if (k < 128) s_l[e][k] = val; else v_l[e][k - 128] = val;
    }
    for (int idx = j; idx < NPB_A * AA; idx += 128) {
        int e = idx / AA, k = idx - e * AA;
        a_l[e][k] = node_attrs[(size_t)(n0 + e) * AA + k];
    }
    __syncthreads();

    float accS[NPB_A] = {0}, accU[NPB_A] = {0};
    float accSV[NPB_A][3] = {{0}}, accUV[NPB_A][3] = {{0}};
    float accSrc[NPB_A] = {0}, accTgt[NPB_A] = {0};

#pragma unroll 4
    for (int i = 0; i < 128; ++i) {
        float ws = Wss[i * 128 + j], wu = Wus[i * 128 + j];
#pragma unroll
        for (int e = 0; e < NPB_A; ++e) {
            float sv = s_l[e][i];
            accS[e] += sv * ws; accU[e] += sv * wu;
        }
    }
#pragma unroll 2
    for (int i = 0; i < 128; ++i) {
        float wsv = Wsv[i * 128 + j], wuv = Wuv[i * 128 + j];
#pragma unroll
        for (int e = 0; e < NPB_A; ++e) {
#pragma unroll
            for (int c = 0; c < 3; ++c) {
                float vv = v_l[e][i * 3 + c];
                accSV[e][c] += vv * wsv; accUV[e][c] += vv * wuv;
            }
        }
    }
#pragma unroll
    for (int i = 0; i < AA; ++i) {
        float w1 = Wsrc[i * 128 + j], w2 = Wtgt[i * 128 + j];
#pragma unroll
        for (int e = 0; e < NPB_A; ++e) {
            float av = a_l[e][i];
            accSrc[e] += av * w1; accTgt[e] += av * w2;
        }
    }

#pragma unroll
    for (int e = 0; e < NPB_A; ++e) {
        size_t n = n0 + e;
        sc_out[n * 512 + j] = accS[e] * INV_SQRT128;
#pragma unroll
        for (int c = 0; c < 3; ++c)
            sc_out[n * 512 + 128 + j * 3 + c] = accSV[e][c] * INV_SQRT128;
        us[n * 128 + j] = accU[e] * INV_SQRT128;
#pragma unroll
        for (int c = 0; c < 3; ++c)
            uv[n * 384 + j * 3 + c] = accUV[e][c] * INV_SQRT128;
        srcEb[n * 128 + j] = f2bf(accSrc[e] * INV_SQRT10);
        tgtEb[n * 128 + j] = f2bf(accTgt[e] * INV_SQRT10);
    }
}

// ---------------------------------------------------------------------------
// Kernel B: per-edge MLP on MFMA. 64 edges/block, 4 waves, 16-row slab each.
// All inter-layer LDS traffic is wave-private => no barriers in GEMM chain.
// ---------------------------------------------------------------------------
#define EBK 64
__global__ __launch_bounds__(256) void edge_mlp(
    const float* __restrict__ edge_attrs, const float* __restrict__ edge_feats,
    const int* __restrict__ edge_index,
    const unsigned short* __restrict__ srcEb, const unsigned short* __restrict__ tgtEb,
    const unsigned short* __restrict__ WB0, const unsigned short* __restrict__ WB1,
    const unsigned short* __restrict__ WB2, const unsigned short* __restrict__ WB3,
    const float* __restrict__ Wd1, const int* __restrict__ pos,
    unsigned short* __restrict__ tpwP, float* __restrict__ metaP)
{
    // strides padded so rows m, m+8 share banks (2-way = free)
    __shared__ __align__(16) unsigned short efb[EBK][296];   // K=288 used
    __shared__ __align__(16) unsigned short h0b[EBK][72];    // K=64 used
    __shared__ __align__(16) unsigned short h1b[EBK][72];
    __shared__ int snd_l[EBK], rcv_l[EBK], slot_l[EBK];
    __shared__ float y_l[EBK][4];

    const int t = threadIdx.x;
    const int l = t & 63;
    const int w = t >> 6;
    const int quad = l >> 4;
    const int lr = l & 15;
    const int e0 = blockIdx.x * EBK;

    if (t < EBK) {
        snd_l[t] = edge_index[e0 + t];
        rcv_l[t] = edge_index[EE + e0 + t];
        slot_l[t] = pos[e0 + t];
    }
    __syncthreads();

    if (t < EBK) {
        float4 ya = *(const float4*)(edge_attrs + (size_t)(e0 + t) * 4);
        y_l[t][0] = ya.x; y_l[t][1] = ya.y; y_l[t][2] = ya.z; y_l[t][3] = ya.w;
        float4 m;
        m.x = __int_as_float(snd_l[t]); m.y = ya.y; m.z = ya.z; m.w = ya.w;
        *(float4*)(metaP + (size_t)slot_l[t] * 8) = m;
        // edge_feats 8 floats -> bf16
        float4 f0 = *(const float4*)(edge_feats + (size_t)(e0 + t) * 8);
        float4 f1 = *(const float4*)(edge_feats + (size_t)(e0 + t) * 8 + 4);
        uint4 o;
        o.x = (unsigned)f2bf(f0.x) | ((unsigned)f2bf(f0.y) << 16);
        o.y = (unsigned)f2bf(f0.z) | ((unsigned)f2bf(f0.w) << 16);
        o.z = (unsigned)f2bf(f1.x) | ((unsigned)f2bf(f1.y) << 16);
        o.w = (unsigned)f2bf(f1.z) | ((unsigned)f2bf(f1.w) << 16);
        *(uint4*)&efb[t][0] = o;
    }
    for (int idx = t; idx < EBK * 16; idx += 256) {
        int e = idx >> 4, c = idx & 15;
        *(uint4*)&efb[e][8 + c * 8] =
            *(const uint4*)(srcEb + (size_t)snd_l[e] * 128 + c * 8);
        *(uint4*)&efb[e][136 + c * 8] =
            *(const uint4*)(tgtEb + (size_t)rcv_l[e] * 128 + c * 8);
    }
    for (int idx = t; idx < EBK * 3; idx += 256) {
        int e = idx / 3, c = idx - e * 3;
        uint4 z; z.x = 0; z.y = 0; z.z = 0; z.w = 0;
        *(uint4*)&efb[e][264 + c * 8] = z;
    }
    __syncthreads();

    const int rb = w * 16;
    int rowr[4], slotr[4];
    float y0r[4];
#pragma unroll
    for (int reg = 0; reg < 4; ++reg) {
        rowr[reg] = rb + quad * 4 + reg;
        slotr[reg] = slot_l[rowr[reg]];
        y0r[reg] = y_l[rowr[reg]][0];
    }
    float wd1v[4];
#pragma unroll
    for (int q2 = 0; q2 < 4; ++q2) wd1v[q2] = Wd1[q2 * 16 + lr] * 0.125f;

    // ---- layer0: ef[64x288] @ WB0[288x128]  (cols 0-63: h0, 64-127: d)
    floatx4 c0[8];
#pragma unroll
    for (int nt = 0; nt < 8; ++nt) c0[nt] = (floatx4){0.f, 0.f, 0.f, 0.f};
    const unsigned short* arow = &efb[rb + lr][quad * 8];
#pragma unroll
    for (int kt = 0; kt < 9; ++kt) {
        short8 af = *(const short8*)(arow + kt * 32);
        const short8* bp = (const short8*)WB0 + (size_t)(kt * 8) * 64 + l;
#pragma unroll
        for (int nt = 0; nt < 8; ++nt) {
            short8 bf = bp[nt * 64];
            c0[nt] = __builtin_amdgcn_mfma_f32_16x16x32_bf16(af, bf, c0[nt], 0, 0, 0);
        }
    }
    // h0 -> LDS (wave-private rows); d-path -> density
    float dp[4] = {0.f, 0.f, 0.f, 0.f};
#pragma unroll
    for (int nt = 0; nt < 4; ++nt) {
#pragma unroll
        for (int reg = 0; reg < 4; ++reg) {
            h0b[rowr[reg]][nt * 16 + lr] = f2bf(silu_f(c0[nt][reg]));
            dp[reg] += silu_f(c0[nt + 4][reg]) * wd1v[nt];
        }
    }
#pragma unroll
    for (int m2 = 1; m2 < 16; m2 <<= 1) {
#pragma unroll
        for (int reg = 0; reg < 4; ++reg) dp[reg] += __shfl_xor(dp[reg], m2);
    }
    if (lr == 0) {
#pragma unroll
        for (int reg = 0; reg < 4; ++reg)
            metaP[(size_t)slotr[reg] * 8 + 4] = tanhf(dp[reg] * dp[reg]);
    }

    const unsigned short* hrow0 = &h0b[rb + lr][quad * 8];
    const unsigned short* hrow1 = &h1b[rb + lr][quad * 8];

    // ---- layer1: h0[64x64] @ WB1[64x64] -> h1
    {
        floatx4 c1[4];
#pragma unroll
        for (int nt = 0; nt < 4; ++nt) c1[nt] = (floatx4){0.f, 0.f, 0.f, 0.f};
#pragma unroll
        for (int kt = 0; kt < 2; ++kt) {
            short8 af = *(const short8*)(hrow0 + kt * 32);
            const short8* bp = (const short8*)WB1 + (size_t)(kt * 4) * 64 + l;
#pragma unroll
            for (int nt = 0; nt < 4; ++nt)
                c1[nt] = __builtin_amdgcn_mfma_f32_16x16x32_bf16(af, bp[nt * 64], c1[nt], 0, 0, 0);
        }
#pragma unroll
        for (int nt = 0; nt < 4; ++nt)
#pragma unroll
            for (int reg = 0; reg < 4; ++reg)
                h1b[rowr[reg]][nt * 16 + lr] = f2bf(silu_f(c1[nt][reg]));
    }

    // ---- layer2: h1 @ WB2 -> h2 (stored back into h0b)
    {
        floatx4 c2[4];
#pragma unroll
        for (int nt = 0; nt < 4; ++nt) c2[nt] = (floatx4){0.f, 0.f, 0.f, 0.f};
#pragma unroll
        for (int kt = 0; kt < 2; ++kt) {
            short8 af = *(const short8*)(hrow1 + kt * 32);
            const short8* bp = (const short8*)WB2 + (size_t)(kt * 4) * 64 + l;
#pragma unroll
            for (int nt = 0; nt < 4; ++nt)
                c2[nt] = __builtin_amdgcn_mfma_f32_16x16x32_bf16(af, bp[nt * 64], c2[nt], 0, 0, 0);
        }
#pragma unroll
        for (int nt = 0; nt < 4; ++nt)
#pragma unroll
            for (int reg = 0; reg < 4; ++reg)
                h0b[rowr[reg]][nt * 16 + lr] = f2bf(silu_f(c2[nt][reg]));
    }

    // ---- layer3: h2[64x64] @ WB3[64x512] -> tpw (scaled, bf16, at CSR slot)
#pragma unroll
    for (int g = 0; g < 4; ++g) {
        floatx4 c3[8];
#pragma unroll
        for (int j2 = 0; j2 < 8; ++j2) c3[j2] = (floatx4){0.f, 0.f, 0.f, 0.f};
#pragma unroll
        for (int kt = 0; kt < 2; ++kt) {
            short8 af = *(const short8*)(hrow0 + kt * 32);
            const short8* bp = (const short8*)WB3 + (size_t)(kt * 32 + g * 8) * 64 + l;
#pragma unroll
            for (int j2 = 0; j2 < 8; ++j2)
                c3[j2] = __builtin_amdgcn_mfma_f32_16x16x32_bf16(af, bp[j2 * 64], c3[j2], 0, 0, 0);
        }
#pragma unroll
        for (int j2 = 0; j2 < 8; ++j2) {
            int nt = g * 8 + j2;
            int q = nt >> 2;
            bool usey0 = !(q & 2);   // q0,1 (w1) and q4,5 (w3) multiply by y0
#pragma unroll
            for (int reg = 0; reg < 4; ++reg) {
                float val = c3[j2][reg] * (usey0 ? y0r[reg] : 1.f);
                tpwP[(size_t)slotr[reg] * 512 + nt * 16 + lr] = f2bf(val);
            }
        }
    }
}

// ---------------------------------------------------------------------------
// Kernel C: per-node gather (no atomics). block = 128 threads, 1 node.
// ---------------------------------------------------------------------------
__global__ __launch_bounds__(128) void node_gather(
    const unsigned short* __restrict__ tpwP, const float* __restrict__ metaP,
    const int* __restrict__ offs,
    const float* __restrict__ us, const float* __restrict__ uv,
    float* __restrict__ msg_s, float* __restrict__ msg_v,
    float* __restrict__ density)
{
    const int n = blockIdx.x;
    const int j = threadIdx.x;
    const int s0 = offs[n], s1 = offs[n + 1];

    float as0 = 0.f, as1 = 0.f;
    float av0x = 0.f, av0y = 0.f, av0z = 0.f;
    float av1x = 0.f, av1y = 0.f, av1z = 0.f;
    float dsum = 0.f;

    for (int s = s0; s < s1; ++s) {
        const float4 m0 = *reinterpret_cast<const float4*>(&metaP[(size_t)s * 8]);
        const float dns = metaP[(size_t)s * 8 + 4];
        const int snd = __float_as_int(m0.x);
        const float y1x = m0.y, y1y = m0.z, y1z = m0.w;
        dsum += dns;

        const float xs = us[(size_t)snd * 128 + j];
        const float* xvp = &uv[(size_t)snd * 384 + 3 * j];
        const float xvx = xvp[0], xvy = xvp[1], xvz = xvp[2];

        const unsigned short* tp = &tpwP[(size_t)s * 512];
        const float w1 = bf2f(tp[j]);
        const float w2 = bf2f(tp[128 + j]);
        const float w3 = bf2f(tp[256 + j]);
        const float w4 = bf2f(tp[384 + j]);

        as0 += w1 * xs;
        as1 += w4 * (xvx * y1x + xvy * y1y + xvz * y1z);
        const float b2 = w2 * xs;
        av0x += b2 * y1x; av0y += b2 * y1y; av0z += b2 * y1z;
        av1x += w3 * xvx; av1y += w3 * xvy; av1z += w3 * xvz;
    }

    msg_s[(size_t)n * 256 + j] = as0;
    msg_s[(size_t)n * 256 + 128 + j] = as1;
    float* mv = &msg_v[(size_t)n * 768];
    mv[3 * j + 0] = av0x; mv[3 * j + 1] = av0y; mv[3 * j + 2] = av0z;
    mv[384 + 3 * j + 0] = av1x; mv[384 + 3 * j + 1] = av1y; mv[384 + 3 * j + 2] = av1z;
    if (j == 0) density[n] = dsum;
}

// ---------------------------------------------------------------------------
// Kernel D: per-node epilogue (W1/Wres, gate, W2) -> out
// ---------------------------------------------------------------------------
#define NPB_C 8
__global__ __launch_bounds__(128) void node_post(
    const float* __restrict__ msg_s, const float* __restrict__ msg_v,
    const float* __restrict__ density,
    const float* __restrict__ us, const float* __restrict__ uv,
    const float* __restrict__ W1s, const float* __restrict__ W1v,
    const float* __restrict__ Wrs, const float* __restrict__ Wrv,
    const float* __restrict__ W2s, const float* __restrict__ W2v,
    const float* __restrict__ alpha_p, const float* __restrict__ beta_p,
    float* __restrict__ out)
{
    __shared__ float ms_l[NPB_C][256];
    __shared__ float mv_l[NPB_C][768];
    __shared__ float us_l[NPB_C][128];
    __shared__ float uv_l[NPB_C][384];
    __shared__ float den_l[NPB_C];
    const int j = threadIdx.x;
    const int n0 = blockIdx.x * NPB_C;
    const float alpha = *alpha_p, beta = *beta_p;

    for (int idx = j; idx < NPB_C * 256; idx += 128) {
        int e = idx >> 8, k = idx & 255;
        ms_l[e][k] = msg_s[(size_t)(n0 + e) * 256 + k];
    }
    for (int idx = j; idx < NPB_C * 768; idx += 128) {
        int e = idx / 768, k = idx - e * 768;
        mv_l[e][k] = msg_v[(size_t)(n0 + e) * 768 + k];
    }
    for (int idx = j; idx < NPB_C * 128; idx += 128) {
        int e = idx >> 7, k = idx & 127;
        us_l[e][k] = us[(size_t)(n0 + e) * 128 + k];
    }
    for (int idx = j; idx < NPB_C * 384; idx += 128) {
        int e = idx / 384, k = idx - e * 384;
        uv_l[e][k] = uv[(size_t)(n0 + e) * 384 + k];
    }
    if (j < NPB_C) den_l[j] = density[n0 + j];
    __syncthreads();

    float mA[NPB_C] = {0}, mB[NPB_C] = {0}, mV[NPB_C][3] = {{0}};
#pragma unroll 2
    for (int i = 0; i < 256; ++i) {
        float w1 = W1s[i * 256 + j], w2 = W1s[i * 256 + 128 + j], wv = W1v[i * 128 + j];
#pragma unroll
        for (int e = 0; e < NPB_C; ++e) {
            float msv = ms_l[e][i];
            mA[e] += msv * w1; mB[e] += msv * w2;
#pragma unroll
            for (int c = 0; c < 3; ++c) mV[e][c] += mv_l[e][i * 3 + c] * wv;
        }
    }
    float rA[NPB_C] = {0}, rB[NPB_C] = {0}, rV[NPB_C][3] = {{0}};
#pragma unroll 2
    for (int i = 0; i < 128; ++i) {
        float w1 = Wrs[i * 256 + j], w2 = Wrs[i * 256 + 128 + j], wv = Wrv[i * 128 + j];
#pragma unroll
        for (int e = 0; e < NPB_C; ++e) {
            float sv = us_l[e][i];
            rA[e] += sv * w1; rB[e] += sv * w2;
#pragma unroll
            for (int c = 0; c < 3; ++c) rV[e][c] += uv_l[e][i * 3 + c] * wv;
        }
    }
    __syncthreads();

#pragma unroll
    for (int e = 0; e < NPB_C; ++e) {
        float invden = 1.f / (den_l[e] * beta + alpha);
        float m1 = mA[e] * 0.0625f * invden + rA[e] * INV_SQRT128;
        float m2 = mB[e] * 0.0625f * invden + rB[e] * INV_SQRT128;
        float gate = sigm_f(m2);
        us_l[e][j] = silu_f(m1);
#pragma unroll
        for (int c = 0; c < 3; ++c)
            uv_l[e][j * 3 + c] = (mV[e][c] * 0.0625f * invden + rV[e][c] * INV_SQRT128) * gate;
    }
    __syncthreads();

    float fS[NPB_C] = {0}, fV[NPB_C][3] = {{0}};
#pragma unroll 2
    for (int i = 0; i < 128; ++i) {
        float w1 = W2s[i * 128 + j], wv = W2v[i * 128 + j];
#pragma unroll
        for (int e = 0; e < NPB_C; ++e) {
            fS[e] += us_l[e][i] * w1;
#pragma unroll
            for (int c = 0; c < 3; ++c) fV[e][c] += uv_l[e][i * 3 + c] * wv;
        }
    }
#pragma unroll
    for (int e = 0; e < NPB_C; ++e) {
        size_t n = n0 + e;
        float4 o;
        o.x = fS[e] * INV_SQRT128;
        o.y = fV[e][0] * INV_SQRT128;
        o.z = fV[e][1] * INV_SQRT128;
        o.w = fV[e][2] * INV_SQRT128;
        reinterpret_cast<float4*>(out)[n * 128 + j] = o;
    }
}

// ---------------------------------------------------------------------------
extern "C" void kernel_launch(void* const* d_in, const int* in_sizes, int n_in,
                              void* d_out, int out_size, void* d_ws, size_t ws_size,
                              hipStream_t stream)
{
    const float* node_attrs = (const float*)d_in[0];
    const float* node_feats = (const float*)d_in[1];
    const float* edge_attrs = (const float*)d_in[2];
    const float* edge_feats = (const float*)d_in[3];
    const int*   edge_index = (const int*)d_in[4];
    const float* W_skip_s = (const float*)d_in[5];
    const float* W_skip_v = (const float*)d_in[6];
    const float* W_up_s   = (const float*)d_in[7];
    const float* W_up_v   = (const float*)d_in[8];
    const float* W_src    = (const float*)d_in[9];
    const float* W_tgt    = (const float*)d_in[10];
    const float* W_r0     = (const float*)d_in[11];
    const float* W_r1     = (const float*)d_in[12];
    const float* W_r2     = (const float*)d_in[13];
    const float* W_r3     = (const float*)d_in[14];
    const float* W_d0     = (const float*)d_in[15];
    const float* W_d1     = (const float*)d_in[16];
    const float* W1_s     = (const float*)d_in[17];
    const float* W1_v     = (const float*)d_in[18];
    const float* Wres_s   = (const float*)d_in[19];
    const float* Wres_v   = (const float*)d_in[20];
    const float* W2_s     = (const float*)d_in[21];
    const float* W2_v     = (const float*)d_in[22];
    const float* alpha_p  = (const float*)d_in[23];
    const float* beta_p   = (const float*)d_in[24];

    float* out = (float*)d_out;
    float* sc_out = out + (size_t)NN * 512;
    float* ws = (float*)d_ws;

    float* us    = ws + WS_US;
    float* uv    = ws + WS_UV;
    unsigned short* srcEb = (unsigned short*)(ws + WS_SRC);
    unsigned short* tgtEb = (unsigned short*)(ws + WS_TGT);
    float* msgS  = ws + WS_MSGS;
    float* msgV  = ws + WS_MSGV;
    float* dens  = ws + WS_DENS;
    int*   counts = (int*)(ws + WS_COUNTS);
    int*   offs   = (int*)(ws + WS_OFFS);
    int*   cursor = (int*)(ws + WS_CURSOR);
    int*   pos    = (int*)(ws + WS_POS);
    float* metaP  = ws + WS_META;
    unsigned short* tpwP = (unsigned short*)(ws + WS_TPW);

    // swizzled weights overlaid on msgS region (consumed by edge_mlp before
    // node_gather overwrites msgS)
    unsigned short* WB0 = (unsigned short*)msgS;
    unsigned short* WB1 = WB0 + 72 * 64 * 8;
    unsigned short* WB2 = WB1 + 8 * 64 * 8;
    unsigned short* WB3 = WB2 + 8 * 64 * 8;

    hipMemsetAsync(counts, 0, (size_t)NN * sizeof(int), stream);

    csr_count<<<EE / 256, 256, 0, stream>>>(edge_index, counts);
    csr_scan<<<1, 1024, 0, stream>>>(counts, offs, cursor);
    csr_scatter<<<EE / 256, 256, 0, stream>>>(edge_index, cursor, pos);

    swizzle_weights<<<38, 256, 0, stream>>>(W_r0, W_d0, W_r1, W_r2, W_r3,
                                            WB0, WB1, WB2, WB3);

    node_pre<<<NN / NPB_A, 128, 0, stream>>>(
        node_attrs, node_feats, W_skip_s, W_skip_v, W_up_s, W_up_v, W_src, W_tgt,
        sc_out, us, uv, srcEb, tgtEb);

    edge_mlp<<<EE / EBK, 256, 0, stream>>>(
        edge_attrs, edge_feats, edge_index, srcEb, tgtEb,
        WB0, WB1, WB2, WB3, W_d1, pos, tpwP, metaP);

    node_gather<<<NN, 128, 0, stream>>>(
        tpwP, metaP, offs, us, uv, msgS, msgV, dens);

    node_post<<<NN / NPB_C, 128, 0, stream>>>(
        msgS, msgV, dens, us, uv, W1_s, W1_v, Wres_s, Wres_v, W2_s, W2_v,
        alpha_p, beta_p, out);
}

// Round 4
// 393.885 us; speedup vs baseline: 5.2863x; 1.5400x over previous
//
#include <hip/hip_runtime.h>

// Problem constants (fixed by the reference)
#define NN 8192
#define EE 131072
#define MUL 128
#define AA 10
#define RB 8
#define DEF 264          // RB + 2*MUL
#define INV_SQRT3 0.5773502691896258f
#define INV_SQRT128 0.08838834764831845f
#define INV_SQRT10 0.31622776601683794f
#define INV_SQRT264 0.06154574548966636f

typedef __attribute__((ext_vector_type(8))) short short8;
typedef __attribute__((ext_vector_type(4))) float floatx4;

// ---------------------------------------------------------------------------
// Workspace layout (float offsets). ~190 MB total.
// ---------------------------------------------------------------------------
#define WS_US     ((size_t)0)                       // N*128 f32
#define WS_UV     (WS_US    + (size_t)NN*128)       // N*384 f32 (xyz interleaved)
#define WS_USB    (WS_UV    + (size_t)NN*384)       // N*128 bf16
#define WS_UVB    (WS_USB   + (size_t)NN*64)        // 3*N*128 bf16 channel-major
#define WS_SRC    (WS_UVB   + (size_t)NN*192)       // N*128 bf16
#define WS_TGT    (WS_SRC   + (size_t)NN*64)        // N*128 bf16
#define WS_MSGSB  (WS_TGT   + (size_t)NN*64)        // N*256 bf16 (invden applied)
#define WS_MSGVB  (WS_MSGSB + (size_t)NN*128)       // 3*N*256 bf16 channel-major
#define WS_GATE   (WS_MSGVB + (size_t)NN*384)       // N*128 f32
#define WS_COUNTS (WS_GATE  + (size_t)NN*128)       // N ints
#define WS_OFFS   (WS_COUNTS+ (size_t)NN)           // N+4 ints
#define WS_CURSOR (WS_OFFS  + (size_t)(NN+4))       // N ints
#define WS_POS    (WS_CURSOR+ (size_t)NN)           // E ints
#define WS_META   (WS_POS   + (size_t)EE)           // E*8 f32
#define WS_TPW    (WS_META  + (size_t)EE*8)         // E*512 bf16
#define WS_WB     (WS_TPW   + (size_t)EE*256)       // edge wfrags 152*512 bf16
#define WS_WP     (WS_WB    + (size_t)152*256)      // post wfrags 352*512 bf16

__device__ __forceinline__ float silu_f(float x) { return x / (1.f + __expf(-x)); }
__device__ __forceinline__ float sigm_f(float x) { return 1.f / (1.f + __expf(-x)); }

__device__ __forceinline__ unsigned short f2bf(float x) {
    union { float f; unsigned u; } uf; uf.f = x;
    unsigned r = uf.u + 0x7FFFu + ((uf.u >> 16) & 1u);   // RNE
    return (unsigned short)(r >> 16);
}
__device__ __forceinline__ float bf2f(unsigned short b) {
    union { unsigned u; float f; } uf; uf.u = ((unsigned)b) << 16;
    return uf.f;
}

// ---------------------------------------------------------------------------
// CSR build: count -> scan -> scatter   (receiver-sorted edge slots)
// ---------------------------------------------------------------------------
__global__ __launch_bounds__(256) void csr_count(
    const int* __restrict__ edge_index, int* __restrict__ counts)
{
    int e = blockIdx.x * 256 + threadIdx.x;
    atomicAdd(&counts[edge_index[EE + e]], 1);
}

__global__ __launch_bounds__(1024) void csr_scan(
    const int* __restrict__ counts, int* __restrict__ offs, int* __restrict__ cursor)
{
    __shared__ int sums[1024];
    const int t = threadIdx.x;
    int local[8];
    int s = 0;
#pragma unroll
    for (int k = 0; k < 8; ++k) { local[k] = s; s += counts[t * 8 + k]; }
    sums[t] = s;
    __syncthreads();
    for (int d = 1; d < 1024; d <<= 1) {
        int v = (t >= d) ? sums[t - d] : 0;
        __syncthreads();
        sums[t] += v;
        __syncthreads();
    }
    int base = (t > 0) ? sums[t - 1] : 0;
#pragma unroll
    for (int k = 0; k < 8; ++k) {
        offs[t * 8 + k] = base + local[k];
        cursor[t * 8 + k] = base + local[k];
    }
    if (t == 1023) offs[8192] = sums[1023];
}

__global__ __launch_bounds__(256) void csr_scatter(
    const int* __restrict__ edge_index, int* __restrict__ cursor, int* __restrict__ pos)
{
    int e = blockIdx.x * 256 + threadIdx.x;
    pos[e] = atomicAdd(&cursor[edge_index[EE + e]], 1);
}

// ---------------------------------------------------------------------------
// Edge weight pre-swizzle into MFMA B-fragment order (bf16, scales folded).
// L0: KT=9 NT=8 (W_r0|W_d0, K 264->288, x INV_SQRT264)     frag 0..71
// L1: KT=2 NT=4 (W_r1 x 0.125)                             frag 72..79
// L2: KT=2 NT=4 (W_r2 x 0.125)                             frag 80..87
// L3: KT=2 NT=32 (W_r3 x 0.125 [q<2] or x0.125/sqrt3)      frag 88..151
// ---------------------------------------------------------------------------
__global__ __launch_bounds__(256) void swizzle_weights(
    const float* __restrict__ Wr0, const float* __restrict__ Wd0,
    const float* __restrict__ Wr1, const float* __restrict__ Wr2,
    const float* __restrict__ Wr3, unsigned short* __restrict__ WBall)
{
    int fid = blockIdx.x * 256 + threadIdx.x;
    int lane = fid & 63;
    int frag = fid >> 6;
    int k0 = (lane >> 4) * 8;
    int n0 = lane & 15;
    unsigned short o[8];

    if (frag < 72) {
        int kt = frag >> 3, nt = frag & 7;
        int n = nt * 16 + n0;
#pragma unroll
        for (int j = 0; j < 8; ++j) {
            int k = kt * 32 + k0 + j;
            float v = 0.f;
            if (k < 264) v = ((n < 64) ? Wr0[k * 64 + n] : Wd0[k * 64 + (n - 64)]) * INV_SQRT264;
            o[j] = f2bf(v);
        }
    } else if (frag < 80) {
        int fl = frag - 72;
        int kt = fl >> 2, nt = fl & 3;
        int n = nt * 16 + n0;
#pragma unroll
        for (int j = 0; j < 8; ++j)
            o[j] = f2bf(Wr1[(kt * 32 + k0 + j) * 64 + n] * 0.125f);
    } else if (frag < 88) {
        int fl = frag - 80;
        int kt = fl >> 2, nt = fl & 3;
        int n = nt * 16 + n0;
#pragma unroll
        for (int j = 0; j < 8; ++j)
            o[j] = f2bf(Wr2[(kt * 32 + k0 + j) * 64 + n] * 0.125f);
    } else {
        int fl = frag - 88;
        int kt = fl >> 5, nt = fl & 31;
        int n = nt * 16 + n0;
        int q = n >> 6;
        float sc = (q < 2) ? 0.125f : 0.125f * INV_SQRT3;
#pragma unroll
        for (int j = 0; j < 8; ++j)
            o[j] = f2bf(Wr3[(kt * 32 + k0 + j) * 512 + n] * sc);
    }
    uint4 pk;
    pk.x = (unsigned)o[0] | ((unsigned)o[1] << 16);
    pk.y = (unsigned)o[2] | ((unsigned)o[3] << 16);
    pk.z = (unsigned)o[4] | ((unsigned)o[5] << 16);
    pk.w = (unsigned)o[6] | ((unsigned)o[7] << 16);
    *(uint4*)(WBall + (size_t)fid * 8) = pk;
}

// ---------------------------------------------------------------------------
// Post weight pre-swizzle.
// WPs [384x256]: [[W1s*0.0625],[Wres_s*INV_SQRT128]]   frag 0..191   (12x16)
// WPv [384x128]: [[W1v*0.0625],[Wres_v*INV_SQRT128]]   frag 192..287 (12x8)
// W2s [128x128] * INV_SQRT128                          frag 288..319 (4x8)
// W2v [128x128] * INV_SQRT128                          frag 320..351 (4x8)
// 352 frags * 64 = 22528 threads = 88 blocks * 256
// ---------------------------------------------------------------------------
__global__ __launch_bounds__(256) void swizzle_post(
    const float* __restrict__ W1s, const float* __restrict__ W1v,
    const float* __restrict__ Wrs, const float* __restrict__ Wrv,
    const float* __restrict__ W2s, const float* __restrict__ W2v,
    unsigned short* __restrict__ WPall)
{
    int fid = blockIdx.x * 256 + threadIdx.x;
    int lane = fid & 63;
    int frag = fid >> 6;
    int k0 = (lane >> 4) * 8;
    int n0 = lane & 15;
    unsigned short o[8];

    if (frag < 192) {
        int kt = frag >> 4, nt = frag & 15;
        int n = nt * 16 + n0;
#pragma unroll
        for (int j = 0; j < 8; ++j) {
            int k = kt * 32 + k0 + j;
            float v = (k < 256) ? W1s[k * 256 + n] * 0.0625f
                                : Wrs[(k - 256) * 256 + n] * INV_SQRT128;
            o[j] = f2bf(v);
        }
    } else if (frag < 288) {
        int fl = frag - 192;
        int kt = fl >> 3, nt = fl & 7;
        int n = nt * 16 + n0;
#pragma unroll
        for (int j = 0; j < 8; ++j) {
            int k = kt * 32 + k0 + j;
            float v = (k < 256) ? W1v[k * 128 + n] * 0.0625f
                                : Wrv[(k - 256) * 128 + n] * INV_SQRT128;
            o[j] = f2bf(v);
        }
    } else if (frag < 320) {
        int fl = frag - 288;
        int kt = fl >> 3, nt = fl & 7;
        int n = nt * 16 + n0;
#pragma unroll
        for (int j = 0; j < 8; ++j)
            o[j] = f2bf(W2s[(kt * 32 + k0 + j) * 128 + n] * INV_SQRT128);
    } else {
        int fl = frag - 320;
        int kt = fl >> 3, nt = fl & 7;
        int n = nt * 16 + n0;
#pragma unroll
        for (int j = 0; j < 8; ++j)
            o[j] = f2bf(W2v[(kt * 32 + k0 + j) * 128 + n] * INV_SQRT128);
    }
    uint4 pk;
    pk.x = (unsigned)o[0] | ((unsigned)o[1] << 16);
    pk.y = (unsigned)o[2] | ((unsigned)o[3] << 16);
    pk.z = (unsigned)o[4] | ((unsigned)o[5] << 16);
    pk.w = (unsigned)o[6] | ((unsigned)o[7] << 16);
    *(uint4*)(WPall + (size_t)fid * 8) = pk;
}

// ---------------------------------------------------------------------------
// Kernel A: per-node precompute.
// ---------------------------------------------------------------------------
#define NPB_A 8
__global__ __launch_bounds__(128) void node_pre(
    const float* __restrict__ node_attrs, const float* __restrict__ node_feats,
    const float* __restrict__ Wss, const float* __restrict__ Wsv,
    const float* __restrict__ Wus, const float* __restrict__ Wuv,
    const float* __restrict__ Wsrc, const float* __restrict__ Wtgt,
    float* __restrict__ sc_out, float* __restrict__ us, float* __restrict__ uv,
    unsigned short* __restrict__ us_b, unsigned short* __restrict__ uv_b,
    unsigned short* __restrict__ srcEb, unsigned short* __restrict__ tgtEb)
{
    __shared__ float s_l[NPB_A][128];
    __shared__ float v_l[NPB_A][384];
    __shared__ float a_l[NPB_A][AA];
    const int j = threadIdx.x;
    const int n0 = blockIdx.x * NPB_A;

    for (int idx = j; idx < NPB_A * 512; idx += 128) {
        int e = idx >> 9, k = idx & 511;
        float val = node_feats[(size_t)(n0 + e) * 512 + k];
        if (k < 128) s_l[e][k] = val; else v_l[e][k - 128] = val;
    }
    for (int idx = j; idx < NPB_A * AA; idx += 128) {
        int e = idx / AA, k = idx - e * AA;
        a_l[e][k] = node_attrs[(size_t)(n0 + e) * AA + k];
    }
    __syncthreads();

    float accS[NPB_A] = {0}, accU[NPB_A] = {0};
    float accSV[NPB_A][3] = {{0}}, accUV[NPB_A][3] = {{0}};
    float accSrc[NPB_A] = {0}, accTgt[NPB_A] = {0};

#pragma unroll 4
    for (int i = 0; i < 128; ++i) {
        float ws = Wss[i * 128 + j], wu = Wus[i * 128 + j];
#pragma unroll
        for (int e = 0; e < NPB_A; ++e) {
            float sv = s_l[e][i];
            accS[e] += sv * ws; accU[e] += sv * wu;
        }
    }
#pragma unroll 2
    for (int i = 0; i < 128; ++i) {
        float wsv = Wsv[i * 128 + j], wuv = Wuv[i * 128 + j];
#pragma unroll
        for (int e = 0; e < NPB_A; ++e) {
#pragma unroll
            for (int c = 0; c < 3; ++c) {
                float vv = v_l[e][i * 3 + c];
                accSV[e][c] += vv * wsv; accUV[e][c] += vv * wuv;
            }
        }
    }
#pragma unroll
    for (int i = 0; i < AA; ++i) {
        float w1 = Wsrc[i * 128 + j], w2 = Wtgt[i * 128 + j];
#pragma unroll
        for (int e = 0; e < NPB_A; ++e) {
            float av = a_l[e][i];
            accSrc[e] += av * w1; accTgt[e] += av * w2;
        }
    }

#pragma unroll
    for (int e = 0; e < NPB_A; ++e) {
        size_t n = n0 + e;
        sc_out[n * 512 + j] = accS[e] * INV_SQRT128;
#pragma unroll
        for (int c = 0; c < 3; ++c)
            sc_out[n * 512 + 128 + j * 3 + c] = accSV[e][c] * INV_SQRT128;
        float usv = accU[e] * INV_SQRT128;
        us[n * 128 + j] = usv;
        us_b[n * 128 + j] = f2bf(usv);
#pragma unroll
        for (int c = 0; c < 3; ++c) {
            float uvv = accUV[e][c] * INV_SQRT128;
            uv[n * 384 + j * 3 + c] = uvv;
            uv_b[((size_t)c * NN + n) * 128 + j] = f2bf(uvv);
        }
        srcEb[n * 128 + j] = f2bf(accSrc[e] * INV_SQRT10);
        tgtEb[n * 128 + j] = f2bf(accTgt[e] * INV_SQRT10);
    }
}

// ---------------------------------------------------------------------------
// Kernel B: per-edge MLP on MFMA. 64 edges/block, 4 waves, 16-row slab each.
// ---------------------------------------------------------------------------
#define EBK 64
__global__ __launch_bounds__(256) void edge_mlp(
    const float* __restrict__ edge_attrs, const float* __restrict__ edge_feats,
    const int* __restrict__ edge_index,
    const unsigned short* __restrict__ srcEb, const unsigned short* __restrict__ tgtEb,
    const unsigned short* __restrict__ WB0, const unsigned short* __restrict__ WB1,
    const unsigned short* __restrict__ WB2, const unsigned short* __restrict__ WB3,
    const float* __restrict__ Wd1, const int* __restrict__ pos,
    unsigned short* __restrict__ tpwP, float* __restrict__ metaP)
{
    __shared__ __align__(16) unsigned short efb[EBK][296];
    __shared__ __align__(16) unsigned short h0b[EBK][72];
    __shared__ __align__(16) unsigned short h1b[EBK][72];
    __shared__ int snd_l[EBK], rcv_l[EBK], slot_l[EBK];
    __shared__ float y_l[EBK][4];

    const int t = threadIdx.x;
    const int l = t & 63;
    const int w = t >> 6;
    const int quad = l >> 4;
    const int lr = l & 15;
    const int e0 = blockIdx.x * EBK;

    if (t < EBK) {
        snd_l[t] = edge_index[e0 + t];
        rcv_l[t] = edge_index[EE + e0 + t];
        slot_l[t] = pos[e0 + t];
    }
    __syncthreads();

    if (t < EBK) {
        float4 ya = *(const float4*)(edge_attrs + (size_t)(e0 + t) * 4);
        y_l[t][0] = ya.x; y_l[t][1] = ya.y; y_l[t][2] = ya.z; y_l[t][3] = ya.w;
        float4 m;
        m.x = __int_as_float(snd_l[t]); m.y = ya.y; m.z = ya.z; m.w = ya.w;
        *(float4*)(metaP + (size_t)slot_l[t] * 8) = m;
        float4 f0 = *(const float4*)(edge_feats + (size_t)(e0 + t) * 8);
        float4 f1 = *(const float4*)(edge_feats + (size_t)(e0 + t) * 8 + 4);
        uint4 o;
        o.x = (unsigned)f2bf(f0.x) | ((unsigned)f2bf(f0.y) << 16);
        o.y = (unsigned)f2bf(f0.z) | ((unsigned)f2bf(f0.w) << 16);
        o.z = (unsigned)f2bf(f1.x) | ((unsigned)f2bf(f1.y) << 16);
        o.w = (unsigned)f2bf(f1.z) | ((unsigned)f2bf(f1.w) << 16);
        *(uint4*)&efb[t][0] = o;
    }
    for (int idx = t; idx < EBK * 16; idx += 256) {
        int e = idx >> 4, c = idx & 15;
        *(uint4*)&efb[e][8 + c * 8] =
            *(const uint4*)(srcEb + (size_t)snd_l[e] * 128 + c * 8);
        *(uint4*)&efb[e][136 + c * 8] =
            *(const uint4*)(tgtEb + (size_t)rcv_l[e] * 128 + c * 8);
    }
    for (int idx = t; idx < EBK * 3; idx += 256) {
        int e = idx / 3, c = idx - e * 3;
        uint4 z; z.x = 0; z.y = 0; z.z = 0; z.w = 0;
        *(uint4*)&efb[e][264 + c * 8] = z;
    }
    __syncthreads();

    const int rb = w * 16;
    int rowr[4], slotr[4];
    float y0r[4];
#pragma unroll
    for (int reg = 0; reg < 4; ++reg) {
        rowr[reg] = rb + quad * 4 + reg;
        slotr[reg] = slot_l[rowr[reg]];
        y0r[reg] = y_l[rowr[reg]][0];
    }
    float wd1v[4];
#pragma unroll
    for (int q2 = 0; q2 < 4; ++q2) wd1v[q2] = Wd1[q2 * 16 + lr] * 0.125f;

    floatx4 c0[8];
#pragma unroll
    for (int nt = 0; nt < 8; ++nt) c0[nt] = (floatx4){0.f, 0.f, 0.f, 0.f};
    const unsigned short* arow = &efb[rb + lr][quad * 8];
#pragma unroll
    for (int kt = 0; kt < 9; ++kt) {
        short8 af = *(const short8*)(arow + kt * 32);
        const short8* bp = (const short8*)WB0 + (size_t)(kt * 8) * 64 + l;
#pragma unroll
        for (int nt = 0; nt < 8; ++nt) {
            short8 bf = bp[nt * 64];
            c0[nt] = __builtin_amdgcn_mfma_f32_16x16x32_bf16(af, bf, c0[nt], 0, 0, 0);
        }
    }
    float dp[4] = {0.f, 0.f, 0.f, 0.f};
#pragma unroll
    for (int nt = 0; nt < 4; ++nt) {
#pragma unroll
        for (int reg = 0; reg < 4; ++reg) {
            h0b[rowr[reg]][nt * 16 + lr] = f2bf(silu_f(c0[nt][reg]));
            dp[reg] += silu_f(c0[nt + 4][reg]) * wd1v[nt];
        }
    }
#pragma unroll
    for (int m2 = 1; m2 < 16; m2 <<= 1) {
#pragma unroll
        for (int reg = 0; reg < 4; ++reg) dp[reg] += __shfl_xor(dp[reg], m2);
    }
    if (lr == 0) {
#pragma unroll
        for (int reg = 0; reg < 4; ++reg)
            metaP[(size_t)slotr[reg] * 8 + 4] = tanhf(dp[reg] * dp[reg]);
    }

    const unsigned short* hrow0 = &h0b[rb + lr][quad * 8];
    const unsigned short* hrow1 = &h1b[rb + lr][quad * 8];

    {
        floatx4 c1[4];
#pragma unroll
        for (int nt = 0; nt < 4; ++nt) c1[nt] = (floatx4){0.f, 0.f, 0.f, 0.f};
#pragma unroll
        for (int kt = 0; kt < 2; ++kt) {
            short8 af = *(const short8*)(hrow0 + kt * 32);
            const short8* bp = (const short8*)WB1 + (size_t)(kt * 4) * 64 + l;
#pragma unroll
            for (int nt = 0; nt < 4; ++nt)
                c1[nt] = __builtin_amdgcn_mfma_f32_16x16x32_bf16(af, bp[nt * 64], c1[nt], 0, 0, 0);
        }
#pragma unroll
        for (int nt = 0; nt < 4; ++nt)
#pragma unroll
            for (int reg = 0; reg < 4; ++reg)
                h1b[rowr[reg]][nt * 16 + lr] = f2bf(silu_f(c1[nt][reg]));
    }

    {
        floatx4 c2[4];
#pragma unroll
        for (int nt = 0; nt < 4; ++nt) c2[nt] = (floatx4){0.f, 0.f, 0.f, 0.f};
#pragma unroll
        for (int kt = 0; kt < 2; ++kt) {
            short8 af = *(const short8*)(hrow1 + kt * 32);
            const short8* bp = (const short8*)WB2 + (size_t)(kt * 4) * 64 + l;
#pragma unroll
            for (int nt = 0; nt < 4; ++nt)
                c2[nt] = __builtin_amdgcn_mfma_f32_16x16x32_bf16(af, bp[nt * 64], c2[nt], 0, 0, 0);
        }
#pragma unroll
        for (int nt = 0; nt < 4; ++nt)
#pragma unroll
            for (int reg = 0; reg < 4; ++reg)
                h0b[rowr[reg]][nt * 16 + lr] = f2bf(silu_f(c2[nt][reg]));
    }

#pragma unroll
    for (int g = 0; g < 4; ++g) {
        floatx4 c3[8];
#pragma unroll
        for (int j2 = 0; j2 < 8; ++j2) c3[j2] = (floatx4){0.f, 0.f, 0.f, 0.f};
#pragma unroll
        for (int kt = 0; kt < 2; ++kt) {
            short8 af = *(const short8*)(hrow0 + kt * 32);
            const short8* bp = (const short8*)WB3 + (size_t)(kt * 32 + g * 8) * 64 + l;
#pragma unroll
            for (int j2 = 0; j2 < 8; ++j2)
                c3[j2] = __builtin_amdgcn_mfma_f32_16x16x32_bf16(af, bp[j2 * 64], c3[j2], 0, 0, 0);
        }
#pragma unroll
        for (int j2 = 0; j2 < 8; ++j2) {
            int nt = g * 8 + j2;
            int q = nt >> 2;
            bool usey0 = !(q & 2);
#pragma unroll
            for (int reg = 0; reg < 4; ++reg) {
                float val = c3[j2][reg] * (usey0 ? y0r[reg] : 1.f);
                tpwP[(size_t)slotr[reg] * 512 + nt * 16 + lr] = f2bf(val);
            }
        }
    }
}

// ---------------------------------------------------------------------------
// Kernel C: per-node gather (no atomics). block = 128 threads, 1 node.
// Applies invden and writes msg_s / msg_v as bf16 (channel-major msg_v).
// ---------------------------------------------------------------------------
__global__ __launch_bounds__(128) void node_gather(
    const unsigned short* __restrict__ tpwP, const float* __restrict__ metaP,
    const int* __restrict__ offs,
    const float* __restrict__ us, const float* __restrict__ uv,
    const float* __restrict__ alpha_p, const float* __restrict__ beta_p,
    unsigned short* __restrict__ msgs_b, unsigned short* __restrict__ msgv_b)
{
    const int n = blockIdx.x;
    const int j = threadIdx.x;
    const int s0 = offs[n], s1 = offs[n + 1];

    float as0 = 0.f, as1 = 0.f;
    float av0x = 0.f, av0y = 0.f, av0z = 0.f;
    float av1x = 0.f, av1y = 0.f, av1z = 0.f;
    float dsum = 0.f;

    for (int s = s0; s < s1; ++s) {
        const float4 m0 = *reinterpret_cast<const float4*>(&metaP[(size_t)s * 8]);
        const float dns = metaP[(size_t)s * 8 + 4];
        const int snd = __float_as_int(m0.x);
        const float y1x = m0.y, y1y = m0.z, y1z = m0.w;
        dsum += dns;

        const float xs = us[(size_t)snd * 128 + j];
        const float* xvp = &uv[(size_t)snd * 384 + 3 * j];
        const float xvx = xvp[0], xvy = xvp[1], xvz = xvp[2];

        const unsigned short* tp = &tpwP[(size_t)s * 512];
        const float w1 = bf2f(tp[j]);
        const float w2 = bf2f(tp[128 + j]);
        const float w3 = bf2f(tp[256 + j]);
        const float w4 = bf2f(tp[384 + j]);

        as0 += w1 * xs;
        as1 += w4 * (xvx * y1x + xvy * y1y + xvz * y1z);
        const float b2 = w2 * xs;
        av0x += b2 * y1x; av0y += b2 * y1y; av0z += b2 * y1z;
        av1x += w3 * xvx; av1y += w3 * xvy; av1z += w3 * xvz;
    }

    const float invden = 1.f / (dsum * (*beta_p) + (*alpha_p));

    msgs_b[(size_t)n * 256 + j]       = f2bf(as0 * invden);
    msgs_b[(size_t)n * 256 + 128 + j] = f2bf(as1 * invden);
    msgv_b[((size_t)0 * NN + n) * 256 + j]       = f2bf(av0x * invden);
    msgv_b[((size_t)0 * NN + n) * 256 + 128 + j] = f2bf(av1x * invden);
    msgv_b[((size_t)1 * NN + n) * 256 + j]       = f2bf(av0y * invden);
    msgv_b[((size_t)1 * NN + n) * 256 + 128 + j] = f2bf(av1y * invden);
    msgv_b[((size_t)2 * NN + n) * 256 + j]       = f2bf(av0z * invden);
    msgv_b[((size_t)2 * NN + n) * 256 + 128 + j] = f2bf(av1z * invden);
}

// ---------------------------------------------------------------------------
// Kernel D1: scalar epilogue on MFMA. 32 nodes/block, 4 waves.
// wave: row-tile rt=w&1 (16 rows), N-half nh=w>>1.
// GEMM1: A=[msgs_b|us_b] (K=384) @ WPs (N=256) -> m_s
//   nh=0 cols 0..127 -> out_s=silu -> LDS;  nh=1 cols 128..255 -> gate -> ws
// GEMM2: out_s (K=128) @ W2s -> f_s -> out[:,:,0]
// ---------------------------------------------------------------------------
#define DNP 32
__global__ __launch_bounds__(256) void post_s(
    const unsigned short* __restrict__ msgs_b, const unsigned short* __restrict__ us_b,
    const unsigned short* __restrict__ WPs, const unsigned short* __restrict__ W2ss,
    float* __restrict__ gate, float* __restrict__ out)
{
    __shared__ __align__(16) unsigned short At[DNP][392];
    __shared__ __align__(16) unsigned short osb[DNP][136];
    const int t = threadIdx.x;
    const int l = t & 63, w = t >> 6;
    const int quad = l >> 4, lr = l & 15;
    const int n0 = blockIdx.x * DNP;
    const int rt = w & 1, nh = w >> 1;

    for (int idx = t; idx < DNP * 48; idx += 256) {
        int r = idx / 48, q = idx - r * 48;
        uint4 v;
        if (q < 32) v = *(const uint4*)(msgs_b + (size_t)(n0 + r) * 256 + q * 8);
        else        v = *(const uint4*)(us_b   + (size_t)(n0 + r) * 128 + (q - 32) * 8);
        *(uint4*)&At[r][q * 8] = v;
    }
    __syncthreads();

    int rowr[4];
#pragma unroll
    for (int reg = 0; reg < 4; ++reg) rowr[reg] = rt * 16 + quad * 4 + reg;

    floatx4 c1[8];
#pragma unroll
    for (int nt = 0; nt < 8; ++nt) c1[nt] = (floatx4){0.f, 0.f, 0.f, 0.f};
    const unsigned short* arow = &At[rt * 16 + lr][quad * 8];
#pragma unroll
    for (int kt = 0; kt < 12; ++kt) {
        short8 af = *(const short8*)(arow + kt * 32);
        const short8* bp = (const short8*)WPs + (size_t)(kt * 16 + nh * 8) * 64 + l;
#pragma unroll
        for (int nt = 0; nt < 8; ++nt)
            c1[nt] = __builtin_amdgcn_mfma_f32_16x16x32_bf16(af, bp[nt * 64], c1[nt], 0, 0, 0);
    }
    if (nh == 0) {
#pragma unroll
        for (int nt = 0; nt < 8; ++nt)
#pragma unroll
            for (int reg = 0; reg < 4; ++reg)
                osb[rowr[reg]][nt * 16 + lr] = f2bf(silu_f(c1[nt][reg]));
    } else {
#pragma unroll
        for (int nt = 0; nt < 8; ++nt)
#pragma unroll
            for (int reg = 0; reg < 4; ++reg)
                gate[(size_t)(n0 + rowr[reg]) * 128 + nt * 16 + lr] = sigm_f(c1[nt][reg]);
    }
    __syncthreads();

    floatx4 c2[4];
#pragma unroll
    for (int nt = 0; nt < 4; ++nt) c2[nt] = (floatx4){0.f, 0.f, 0.f, 0.f};
    const unsigned short* arow2 = &osb[rt * 16 + lr][quad * 8];
#pragma unroll
    for (int kt = 0; kt < 4; ++kt) {
        short8 af = *(const short8*)(arow2 + kt * 32);
        const short8* bp = (const short8*)W2ss + (size_t)(kt * 8 + nh * 4) * 64 + l;
#pragma unroll
        for (int nt = 0; nt < 4; ++nt)
            c2[nt] = __builtin_amdgcn_mfma_f32_16x16x32_bf16(af, bp[nt * 64], c2[nt], 0, 0, 0);
    }
#pragma unroll
    for (int nt = 0; nt < 4; ++nt)
#pragma unroll
        for (int reg = 0; reg < 4; ++reg)
            out[(size_t)(n0 + rowr[reg]) * 512 + (nh * 64 + nt * 16 + lr) * 4] = c2[nt][reg];
}

// ---------------------------------------------------------------------------
// Kernel D2: vector epilogue on MFMA. 32 rows/block (one channel c), 4 waves.
// GEMM1: A=[msgv_b|uv_b] (K=384) @ WPv (N=128) -> m_v; *gate; -> LDS bf16
// GEMM2: out_v (K=128) @ W2v -> f_v -> out[:,:,1+c]
// ---------------------------------------------------------------------------
__global__ __launch_bounds__(256) void post_v(
    const unsigned short* __restrict__ msgv_b, const unsigned short* __restrict__ uv_b,
    const unsigned short* __restrict__ WPv, const unsigned short* __restrict__ W2vs,
    const float* __restrict__ gate, float* __restrict__ out)
{
    __shared__ __align__(16) unsigned short At[DNP][392];
    __shared__ __align__(16) unsigned short ovb[DNP][136];
    const int t = threadIdx.x;
    const int l = t & 63, w = t >> 6;
    const int quad = l >> 4, lr = l & 15;
    const int c = blockIdx.x >> 8;            // 256 blocks per channel
    const int n0 = (blockIdx.x & 255) * DNP;
    const int rt = w & 1, nh = w >> 1;

    for (int idx = t; idx < DNP * 48; idx += 256) {
        int r = idx / 48, q = idx - r * 48;
        uint4 v;
        if (q < 32) v = *(const uint4*)(msgv_b + ((size_t)c * NN + n0 + r) * 256 + q * 8);
        else        v = *(const uint4*)(uv_b   + ((size_t)c * NN + n0 + r) * 128 + (q - 32) * 8);
        *(uint4*)&At[r][q * 8] = v;
    }
    __syncthreads();

    int rowr[4];
#pragma unroll
    for (int reg = 0; reg < 4; ++reg) rowr[reg] = rt * 16 + quad * 4 + reg;

    floatx4 c1[4];
#pragma unroll
    for (int nt = 0; nt < 4; ++nt) c1[nt] = (floatx4){0.f, 0.f, 0.f, 0.f};
    const unsigned short* arow = &At[rt * 16 + lr][quad * 8];
#pragma unroll
    for (int kt = 0; kt < 12; ++kt) {
        short8 af = *(const short8*)(arow + kt * 32);
        const short8* bp = (const short8*)WPv + (size_t)(kt * 8 + nh * 4) * 64 + l;
#pragma unroll
        for (int nt = 0; nt < 4; ++nt)
            c1[nt] = __builtin_amdgcn_mfma_f32_16x16x32_bf16(af, bp[nt * 64], c1[nt], 0, 0, 0);
    }
#pragma unroll
    for (int nt = 0; nt < 4; ++nt)
#pragma unroll
        for (int reg = 0; reg < 4; ++reg) {
            int col = nh * 64 + nt * 16 + lr;
            float g = gate[(size_t)(n0 + rowr[reg]) * 128 + col];
            ovb[rowr[reg]][col] = f2bf(c1[nt][reg] * g);
        }
    __syncthreads();

    floatx4 c2[4];
#pragma unroll
    for (int nt = 0; nt < 4; ++nt) c2[nt] = (floatx4){0.f, 0.f, 0.f, 0.f};
    const unsigned short* arow2 = &ovb[rt * 16 + lr][quad * 8];
#pragma unroll
    for (int kt = 0; kt < 4; ++kt) {
        short8 af = *(const short8*)(arow2 + kt * 32);
        const short8* bp = (const short8*)W2vs + (size_t)(kt * 8 + nh * 4) * 64 + l;
#pragma unroll
        for (int nt = 0; nt < 4; ++nt)
            c2[nt] = __builtin_amdgcn_mfma_f32_16x16x32_bf16(af, bp[nt * 64], c2[nt], 0, 0, 0);
    }
#pragma unroll
    for (int nt = 0; nt < 4; ++nt)
#pragma unroll
        for (int reg = 0; reg < 4; ++reg)
            out[(size_t)(n0 + rowr[reg]) * 512 + (nh * 64 + nt * 16 + lr) * 4 + 1 + c]
                = c2[nt][reg];
}

// ---------------------------------------------------------------------------
extern "C" void kernel_launch(void* const* d_in, const int* in_sizes, int n_in,
                              void* d_out, int out_size, void* d_ws, size_t ws_size,
                              hipStream_t stream)
{
    const float* node_attrs = (const float*)d_in[0];
    const float* node_feats = (const float*)d_in[1];
    const float* edge_attrs = (const float*)d_in[2];
    const float* edge_feats = (const float*)d_in[3];
    const int*   edge_index = (const int*)d_in[4];
    const float* W_skip_s = (const float*)d_in[5];
    const float* W_skip_v = (const float*)d_in[6];
    const float* W_up_s   = (const float*)d_in[7];
    const float* W_up_v   = (const float*)d_in[8];
    const float* W_src    = (const float*)d_in[9];
    const float* W_tgt    = (const float*)d_in[10];
    const float* W_r0     = (const float*)d_in[11];
    const float* W_r1     = (const float*)d_in[12];
    const float* W_r2     = (const float*)d_in[13];
    const float* W_r3     = (const float*)d_in[14];
    const float* W_d0     = (const float*)d_in[15];
    const float* W_d1     = (const float*)d_in[16];
    const float* W1_s     = (const float*)d_in[17];
    const float* W1_v     = (const float*)d_in[18];
    const float* Wres_s   = (const float*)d_in[19];
    const float* Wres_v   = (const float*)d_in[20];
    const float* W2_s     = (const float*)d_in[21];
    const float* W2_v     = (const float*)d_in[22];
    const float* alpha_p  = (const float*)d_in[23];
    const float* beta_p   = (const float*)d_in[24];

    float* out = (float*)d_out;
    float* sc_out = out + (size_t)NN * 512;
    float* ws = (float*)d_ws;

    float* us    = ws + WS_US;
    float* uv    = ws + WS_UV;
    unsigned short* us_b  = (unsigned short*)(ws + WS_USB);
    unsigned short* uv_b  = (unsigned short*)(ws + WS_UVB);
    unsigned short* srcEb = (unsigned short*)(ws + WS_SRC);
    unsigned short* tgtEb = (unsigned short*)(ws + WS_TGT);
    unsigned short* msgs_b = (unsigned short*)(ws + WS_MSGSB);
    unsigned short* msgv_b = (unsigned short*)(ws + WS_MSGVB);
    float* gate  = ws + WS_GATE;
    int*   counts = (int*)(ws + WS_COUNTS);
    int*   offs   = (int*)(ws + WS_OFFS);
    int*   cursor = (int*)(ws + WS_CURSOR);
    int*   pos    = (int*)(ws + WS_POS);
    float* metaP  = ws + WS_META;
    unsigned short* tpwP = (unsigned short*)(ws + WS_TPW);
    unsigned short* WBall = (unsigned short*)(ws + WS_WB);
    unsigned short* WB0 = WBall;
    unsigned short* WB1 = WB0 + (size_t)72 * 512;
    unsigned short* WB2 = WB1 + (size_t)8 * 512;
    unsigned short* WB3 = WB2 + (size_t)8 * 512;
    unsigned short* WPall = (unsigned short*)(ws + WS_WP);
    unsigned short* WPs  = WPall;
    unsigned short* WPv  = WPs + (size_t)192 * 512;
    unsigned short* W2ss = WPv + (size_t)96 * 512;
    unsigned short* W2vs = W2ss + (size_t)32 * 512;

    hipMemsetAsync(counts, 0, (size_t)NN * sizeof(int), stream);

    csr_count<<<EE / 256, 256, 0, stream>>>(edge_index, counts);
    csr_scan<<<1, 1024, 0, stream>>>(counts, offs, cursor);
    csr_scatter<<<EE / 256, 256, 0, stream>>>(edge_index, cursor, pos);

    swizzle_weights<<<38, 256, 0, stream>>>(W_r0, W_d0, W_r1, W_r2, W_r3, WBall);
    swizzle_post<<<88, 256, 0, stream>>>(W1_s, W1_v, Wres_s, Wres_v, W2_s, W2_v, WPall);

    node_pre<<<NN / NPB_A, 128, 0, stream>>>(
        node_attrs, node_feats, W_skip_s, W_skip_v, W_up_s, W_up_v, W_src, W_tgt,
        sc_out, us, uv, us_b, uv_b, srcEb, tgtEb);

    edge_mlp<<<EE / EBK, 256, 0, stream>>>(
        edge_attrs, edge_feats, edge_index, srcEb, tgtEb,
        WB0, WB1, WB2, WB3, W_d1, pos, tpwP, metaP);

    node_gather<<<NN, 128, 0, stream>>>(
        tpwP, metaP, offs, us, uv, alpha_p, beta_p, msgs_b, msgv_b);

    post_s<<<NN / DNP, 256, 0, stream>>>(msgs_b, us_b, WPs, W2ss, gate, out);
    post_v<<<3 * NN / DNP, 256, 0, stream>>>(msgv_b, uv_b, WPv, W2vs, gate, out);
}